// Round 12
// baseline (174.147 us; speedup 1.0000x reference)
//
#include <hip/hip_runtime.h>
#include <hip/hip_bf16.h>

#define BB 4
#define SS 32
#define HH 8
#define LL 128
#define DD 512
#define DI 2048
#define EPSN 1e-6f
#define INV_TEMP 0.04419417382415922f   // 1/sqrt(512)

#define NLOGIT_BLK 4096                  // B*S*L / 4 waves
#define NCAST_GRAN ((DI*DD/4)*2 + (DD*DD/4))   // 589824 float4 granules
#define NCAST_BLK (NCAST_GRAN / 256)     // 2304

typedef __attribute__((ext_vector_type(8))) short short8;
typedef __attribute__((ext_vector_type(4))) float float4v;

static __device__ __forceinline__ unsigned short f2b(float f) {
  __hip_bfloat16 h = __float2bfloat16(f);
  return *(unsigned short*)&h;
}

// Fragment-packed GLOBAL layout (r10-proven): element (m,k) of (M x K) at
//   ((((m>>4)*(K/32) + (k>>5))*4 + ((k>>3)&3))*16 + (m&15))*8 + (k&7)
// -> one MFMA B/A fragment = one contiguous 1 KB wave read.
static __device__ __forceinline__ size_t pk(int m, int k, int K) {
  return ((((size_t)(m >> 4) * (K >> 5) + (k >> 5)) * 4 + ((k >> 3) & 3)) * 16
          + (m & 15)) * 8 + (k & 7);
}

// LDS 8-row packed A layout: element (row,k), rows 0..7 (lanes 8-15 dup):
//   (((k>>5)*4 + ((k>>3)&3))*8 + row)*8 + (k&7)
static __device__ __forceinline__ int lds8(int row, int k) {
  return (((k >> 5) * 4 + ((k >> 3) & 3)) * 8 + row) * 8 + (k & 7);
}

// ---------------------------------------------------------------------------
// K1: fused [logits] + [weight cast -> fragment-packed bf16].  (r10, proven)
// ---------------------------------------------------------------------------
__global__ __launch_bounds__(256) void pre_kernel(
    const float* __restrict__ x, const int* __restrict__ mask,
    const float* __restrict__ w, const float* __restrict__ w1,
    const float* __restrict__ w2, const float* __restrict__ v_w,
    unsigned short* __restrict__ w1b, unsigned short* __restrict__ w2b,
    unsigned short* __restrict__ v_wb, float* __restrict__ logits) {
  int blk = blockIdx.x;
  if (blk < NLOGIT_BLK) {
    int wv = threadIdx.x >> 6, lane = threadIdx.x & 63;
    int p  = blk * 4 + wv;
    int bs = p >> 7, l = p & (LL - 1);

    const float4* xr = (const float4*)(x + ((size_t)bs * LL + l) * DD) + lane * 2;
    float4 x0 = xr[0], x1 = xr[1];

    float acc[HH];
#pragma unroll
    for (int h = 0; h < HH; ++h) {
      const float4* wr = (const float4*)(w + ((size_t)h * LL + l) * DD) + lane * 2;
      float4 w0 = wr[0], w1v = wr[1];
      acc[h] = x0.x * w0.x + x0.y * w0.y + x0.z * w0.z + x0.w * w0.w +
               x1.x * w1v.x + x1.y * w1v.y + x1.z * w1v.z + x1.w * w1v.w;
    }
#pragma unroll
    for (int off = 32; off > 0; off >>= 1) {
#pragma unroll
      for (int h = 0; h < HH; ++h) acc[h] += __shfl_xor(acc[h], off);
    }
    if (lane == 0) {
      int msk = mask[bs * LL + l];
#pragma unroll
      for (int h = 0; h < HH; ++h) {
        float lg = msk ? acc[h] * INV_TEMP : -1e9f;
        logits[((size_t)bs * HH + h) * LL + l] = lg;
      }
    }
  } else {
    const int n1 = (DI * DD) / 4;    // w1 granules (N=2048,K=512)
    const int n2 = n1;               // w2 granules (N=512, K=2048)
    int i = (blk - NLOGIT_BLK) * 256 + threadIdx.x;
    float4 v;
    unsigned short* dst;
    size_t base;
    if (i < n1) {
      v = ((const float4*)w1)[i];
      dst = w1b;
      base = pk(i >> 7, (i & 127) * 4, DD);
    } else if (i < n1 + n2) {
      int j = i - n1;
      v = ((const float4*)w2)[j];
      dst = w2b;
      base = pk(j >> 9, (j & 511) * 4, DI);
    } else {
      int j = i - n1 - n2;
      v = ((const float4*)v_w)[j];
      dst = v_wb;
      base = pk(j >> 7, (j & 127) * 4, DD);
    }
    dst[base + 0] = f2b(v.x);
    dst[base + 1] = f2b(v.y);
    dst[base + 2] = f2b(v.z);
    dst[base + 3] = f2b(v.w);
  }
}

// ---------------------------------------------------------------------------
// K2: fused per-(b,s) chain.  128 blocks x 1024 threads (16 waves).
//   P0: softmax (waves 0-7, one head each) -> attn out + sattn LDS
//   P1: xa[h][e] = sum_l attn*x  (l-split x2, combine, pack bf16 -> sxap)
//   P2: v-proj MFMA  o = xa @ v_w^T   (wave owns 32 N-cols)
//   P3: mid-LN (waves 0-7) -> sOln fp32 (residual) + sAln packed bf16
//   P4: gemm1+ReLU  h1 = relu(xln@w1^T+b1) -> sH1 packed LDS (32 KB)
//   P5: gemm2  y = h1 @ w2^T  (wave owns 32 N-cols)
//   P6: final LN( y + b2 + sOln ) -> y_out
// All MFMA B-operands: coalesced 1 KB packed global reads (L2-resident).
// ---------------------------------------------------------------------------
__global__ __launch_bounds__(1024, 4) void fused_kernel(
    const float* __restrict__ x, const float* __restrict__ logits,
    const unsigned short* __restrict__ v_wb, const float* __restrict__ ln_g,
    const float* __restrict__ ln_b, const unsigned short* __restrict__ w1b,
    const float* __restrict__ b1, const unsigned short* __restrict__ w2b,
    const float* __restrict__ b2, const float* __restrict__ fln_g,
    const float* __restrict__ fln_b, float* __restrict__ attn_out,
    float* __restrict__ y_out) {
  int bs = blockIdx.x;
  int t = threadIdx.x, wv = t >> 6, lane = t & 63;
  int lm = lane & 15, lq = lane >> 4;

  __shared__ __attribute__((aligned(16))) char smem[86016];
  float*          sattn = (float*)(smem);                   // [128][8]  4 KB
  unsigned short* sxap  = (unsigned short*)(smem + 4096);   // packed xa 8 KB
  unsigned short* sAln  = (unsigned short*)(smem + 12288);  // packed xln 8 KB
  float*          sOln  = (float*)(smem + 20480);           // [8][512] 16 KB
  float*          sxa2  = (float*)(smem + 36864);           // [2][8][512] 32 KB
  unsigned short* sH1   = (unsigned short*)(smem + 36864);  // alias: packed h1 32 KB
  float*          sO    = (float*)(smem + 69632);           // [8][512] 16 KB
  float*          sY2   = (float*)(smem + 69632);           // alias

  // ---- P0: softmax, waves 0-7 handle head wv ----
  if (wv < HH) {
    const float* lg = logits + ((size_t)bs * HH + wv) * LL;
    float v0 = lg[lane], v1 = lg[lane + 64];
    float m = fmaxf(v0, v1);
#pragma unroll
    for (int off = 32; off > 0; off >>= 1) m = fmaxf(m, __shfl_xor(m, off));
    float e0 = __expf(v0 - m), e1 = __expf(v1 - m);
    float s = e0 + e1;
#pragma unroll
    for (int off = 32; off > 0; off >>= 1) s += __shfl_xor(s, off);
    float inv = 1.f / s;
    e0 *= inv; e1 *= inv;
    sattn[lane * HH + wv]       = e0;
    sattn[(lane + 64) * HH + wv] = e1;
    float* ao = attn_out + ((size_t)bs * HH + wv) * LL;
    ao[lane]      = e0;
    ao[lane + 64] = e1;
  }
  __syncthreads();

  // ---- P1: xa; thread owns column e, half the l-range ----
  {
    int e = t & 511, lseg = t >> 9;
    const float* xb = x + (size_t)bs * LL * DD;
    float acc[HH];
#pragma unroll
    for (int h = 0; h < HH; ++h) acc[h] = 0.f;
    int l0 = lseg * 64;
    for (int l = l0; l < l0 + 64; ++l) {
      float xv = xb[(size_t)l * DD + e];
      float4 a0 = *(const float4*)&sattn[l * HH];
      float4 a1 = *(const float4*)&sattn[l * HH + 4];
      acc[0] += a0.x * xv; acc[1] += a0.y * xv;
      acc[2] += a0.z * xv; acc[3] += a0.w * xv;
      acc[4] += a1.x * xv; acc[5] += a1.y * xv;
      acc[6] += a1.z * xv; acc[7] += a1.w * xv;
    }
#pragma unroll
    for (int h = 0; h < HH; ++h) sxa2[(lseg * HH + h) * DD + e] = acc[h];
  }
  __syncthreads();
  if (t < DD) {
#pragma unroll
    for (int h = 0; h < HH; ++h)
      sxap[lds8(h, t)] = f2b(sxa2[h * DD + t] + sxa2[(HH + h) * DD + t]);
  }
  __syncthreads();

  // ---- P2: v-proj; wave owns cols [wv*32, +32) (2 n-frags) ----
  {
    const short8* B8 = (const short8*)v_wb;
    float4v acc[2];
    acc[0] = (float4v){0.f, 0.f, 0.f, 0.f};
    acc[1] = (float4v){0.f, 0.f, 0.f, 0.f};
#pragma unroll 4
    for (int c = 0; c < 16; ++c) {
      short8 a = *(const short8*)&sxap[(((c * 4 + lq) * 8) + (lm & 7)) * 8];
#pragma unroll
      for (int nf = 0; nf < 2; ++nf) {
        short8 b = B8[((size_t)(wv * 2 + nf) * 16 + c) * 64 + lane];
        acc[nf] = __builtin_amdgcn_mfma_f32_16x16x32_bf16(a, b, acc[nf], 0, 0, 0);
      }
    }
    if (lq < 2) {
#pragma unroll
      for (int nf = 0; nf < 2; ++nf) {
        int col = wv * 32 + nf * 16 + lm;
#pragma unroll
        for (int r = 0; r < 4; ++r)
          sO[(lq * 4 + r) * DD + col] = acc[nf][r];
      }
    }
  }
  __syncthreads();

  // ---- P3: mid LN, waves 0-7 handle row wv ----
  if (wv < HH) {
    int row = wv;
    float vals[8];
    float sum = 0.f, sq = 0.f;
#pragma unroll
    for (int k = 0; k < 8; ++k) {
      float v = sO[row * DD + lane + 64 * k];
      vals[k] = v;
      sum += v;
      sq += v * v;
    }
#pragma unroll
    for (int off = 32; off > 0; off >>= 1) {
      sum += __shfl_xor(sum, off);
      sq  += __shfl_xor(sq, off);
    }
    float mu  = sum * (1.f / DD);
    float var = sq * (1.f / DD) - mu * mu;
    float rs  = rsqrtf(var + EPSN);
#pragma unroll
    for (int k = 0; k < 8; ++k) {
      int d = lane + 64 * k;
      float v = (vals[k] - mu) * rs * ln_g[d] + ln_b[d];
      sOln[row * DD + d] = v;
      sAln[lds8(row, d)] = f2b(v);
    }
  }
  __syncthreads();

  // ---- P4: gemm1+ReLU; wave owns cols [wv*128, +128) (8 n-frags) ----
  {
    const short8* B8 = (const short8*)w1b;
    float4v acc[8];
#pragma unroll
    for (int nf = 0; nf < 8; ++nf) acc[nf] = (float4v){0.f, 0.f, 0.f, 0.f};
#pragma unroll 2
    for (int c = 0; c < 16; ++c) {
      short8 a = *(const short8*)&sAln[(((c * 4 + lq) * 8) + (lm & 7)) * 8];
#pragma unroll
      for (int nf = 0; nf < 8; ++nf) {
        short8 b = B8[((size_t)(wv * 8 + nf) * 16 + c) * 64 + lane];
        acc[nf] = __builtin_amdgcn_mfma_f32_16x16x32_bf16(a, b, acc[nf], 0, 0, 0);
      }
    }
    if (lq < 2) {
#pragma unroll
      for (int nf = 0; nf < 8; ++nf) {
        int col = wv * 128 + nf * 16 + lm;
        float bb = b1[col];
#pragma unroll
        for (int r = 0; r < 4; ++r)
          sH1[lds8(lq * 4 + r, col)] = f2b(fmaxf(acc[nf][r] + bb, 0.f));
      }
    }
  }
  __syncthreads();

  // ---- P5: gemm2; wave owns cols [wv*32, +32) (2 n-frags), K=2048 ----
  {
    const short8* B8 = (const short8*)w2b;
    float4v acc[2];
    acc[0] = (float4v){0.f, 0.f, 0.f, 0.f};
    acc[1] = (float4v){0.f, 0.f, 0.f, 0.f};
#pragma unroll 4
    for (int c = 0; c < 64; ++c) {
      short8 a = *(const short8*)&sH1[(((c * 4 + lq) * 8) + (lm & 7)) * 8];
#pragma unroll
      for (int nf = 0; nf < 2; ++nf) {
        short8 b = B8[((size_t)(wv * 2 + nf) * 64 + c) * 64 + lane];
        acc[nf] = __builtin_amdgcn_mfma_f32_16x16x32_bf16(a, b, acc[nf], 0, 0, 0);
      }
    }
    __syncthreads();   // sH1 (aliased) fully consumed before sY2 writes? sY2 is
                       // a different region (69632); sync guards sO->sY2 reuse.
    if (lq < 2) {
#pragma unroll
      for (int nf = 0; nf < 2; ++nf) {
        int col = wv * 32 + nf * 16 + lm;
#pragma unroll
        for (int r = 0; r < 4; ++r)
          sY2[(lq * 4 + r) * DD + col] = acc[nf][r];
      }
    }
  }
  __syncthreads();

  // ---- P6: final LN, waves 0-7 handle row wv ----
  if (wv < HH) {
    int row = wv;
    float vals[8];
    float sum = 0.f, sq = 0.f;
#pragma unroll
    for (int k = 0; k < 8; ++k) {
      int d = lane + 64 * k;
      float v = sY2[row * DD + d] + b2[d] + sOln[row * DD + d];
      vals[k] = v;
      sum += v;
      sq += v * v;
    }
#pragma unroll
    for (int off = 32; off > 0; off >>= 1) {
      sum += __shfl_xor(sum, off);
      sq  += __shfl_xor(sq, off);
    }
    float mu  = sum * (1.f / DD);
    float var = sq * (1.f / DD) - mu * mu;
    float rs  = rsqrtf(var + EPSN);
    float* yo = y_out + ((size_t)bs * HH + row) * DD;
#pragma unroll
    for (int k = 0; k < 8; ++k) {
      int d = lane + 64 * k;
      yo[d] = (vals[k] - mu) * rs * fln_g[d] + fln_b[d];
    }
  }
}

extern "C" void kernel_launch(void* const* d_in, const int* in_sizes, int n_in,
                              void* d_out, int out_size, void* d_ws, size_t ws_size,
                              hipStream_t stream) {
  const float* x     = (const float*)d_in[0];
  const int*   mask  = (const int*)d_in[1];
  const float* w     = (const float*)d_in[2];
  const float* v_w   = (const float*)d_in[3];
  const float* ln_g  = (const float*)d_in[4];
  const float* ln_b  = (const float*)d_in[5];
  const float* w1    = (const float*)d_in[6];
  const float* b1    = (const float*)d_in[7];
  const float* w2    = (const float*)d_in[8];
  const float* b2    = (const float*)d_in[9];
  const float* fln_g = (const float*)d_in[10];
  const float* fln_b = (const float*)d_in[11];

  float* y    = (float*)d_out;
  float* attn = y + (size_t)BB * SS * HH * DD;

  // workspace layout (bytes)
  char* ws = (char*)d_ws;
  unsigned short* w1b    = (unsigned short*)(ws);               // 2 MB
  unsigned short* w2b    = (unsigned short*)(ws + 2097152);     // 2 MB
  unsigned short* v_wb   = (unsigned short*)(ws + 4194304);     // 512 KB
  float*          logits = (float*)(ws + 4718592);              // 512 KB

  pre_kernel<<<NLOGIT_BLK + NCAST_BLK, 256, 0, stream>>>(
      x, mask, w, w1, w2, v_w, w1b, w2b, v_wb, logits);
  fused_kernel<<<BB * SS, 1024, 0, stream>>>(
      x, logits, v_wb, ln_g, ln_b, w1b, b1, w2b, b2, fln_g, fln_b, attn, y);
}

// Round 13
// 149.872 us; speedup vs baseline: 1.1620x; 1.1620x over previous
//
#include <hip/hip_runtime.h>
#include <hip/hip_bf16.h>

#define BB 4
#define SS 32
#define HH 8
#define LL 128
#define DD 512
#define DI 2048
#define EPSN 1e-6f
#define INV_TEMP 0.04419417382415922f   // 1/sqrt(512)

#define NLOGW_BLK 512                    // 2048 wave-tasks: (l, bs-group-of-8)
#define NCAST_GRAN ((DI*DD/4)*2 + (DD*DD/4))   // 589824 float4 granules
#define NCAST_BLK (NCAST_GRAN / 256)     // 2304

#define NROW (BB*SS*HH)                  // 1024 rows
#define SLICE ((size_t)NROW * DD)        // floats per K-split partial

typedef __attribute__((ext_vector_type(8))) short short8;
typedef __attribute__((ext_vector_type(4))) float float4v;

static __device__ __forceinline__ unsigned short f2b(float f) {
  __hip_bfloat16 h = __float2bfloat16(f);
  return *(unsigned short*)&h;
}

// Fragment-packed layout (r10-proven): element (m,k) of an (M x K) operand at
//   ((((m>>4)*(K/32) + (k>>5))*4 + ((k>>3)&3))*16 + (m&15))*8 + (k&7)
// -> one MFMA fragment = one contiguous 1 KB wave read.
static __device__ __forceinline__ size_t pk(int m, int k, int K) {
  return ((((size_t)(m >> 4) * (K >> 5) + (k >> 5)) * 4 + ((k >> 3) & 3)) * 16
          + (m & 15)) * 8 + (k & 7);
}

// ---------------------------------------------------------------------------
// K1: fused [logits] + [weight cast -> fragment-packed bf16].
// Logits re-tiled (r13): wave per (l, bs-group-of-8); w rows register-cached
// once per wave (w traffic 268 MB -> 33 MB vs r10).
// ---------------------------------------------------------------------------
__global__ __launch_bounds__(256) void pre_kernel(
    const float* __restrict__ x, const int* __restrict__ mask,
    const float* __restrict__ w, const float* __restrict__ w1,
    const float* __restrict__ w2, const float* __restrict__ v_w,
    unsigned short* __restrict__ w1b, unsigned short* __restrict__ w2b,
    unsigned short* __restrict__ v_wb, float* __restrict__ logits) {
  int blk = blockIdx.x;
  if (blk < NLOGW_BLK) {
    int wv = threadIdx.x >> 6, lane = threadIdx.x & 63;
    int p   = blk * 4 + wv;          // 0..2047
    int l   = p >> 4;                // 0..127
    int bsg = p & 15;                // bs group: 8 consecutive bs

    // register-cache the 8 w rows for this l (16 float4 loads)
    float4 wr[HH][2];
#pragma unroll
    for (int h = 0; h < HH; ++h) {
      const float4* wp = (const float4*)(w + ((size_t)h * LL + l) * DD) + lane * 2;
      wr[h][0] = wp[0];
      wr[h][1] = wp[1];
    }

#pragma unroll 2
    for (int i = 0; i < 8; ++i) {
      int bs = bsg * 8 + i;
      const float4* xr = (const float4*)(x + ((size_t)bs * LL + l) * DD) + lane * 2;
      float4 x0 = xr[0], x1 = xr[1];
      float acc[HH];
#pragma unroll
      for (int h = 0; h < HH; ++h) {
        acc[h] = x0.x * wr[h][0].x + x0.y * wr[h][0].y +
                 x0.z * wr[h][0].z + x0.w * wr[h][0].w +
                 x1.x * wr[h][1].x + x1.y * wr[h][1].y +
                 x1.z * wr[h][1].z + x1.w * wr[h][1].w;
      }
#pragma unroll
      for (int off = 32; off > 0; off >>= 1) {
#pragma unroll
        for (int h = 0; h < HH; ++h) acc[h] += __shfl_xor(acc[h], off);
      }
      if (lane == 0) {
        int msk = mask[bs * LL + l];
#pragma unroll
        for (int h = 0; h < HH; ++h) {
          float lg = msk ? acc[h] * INV_TEMP : -1e9f;
          logits[((size_t)bs * HH + h) * LL + l] = lg;
        }
      }
    }
  } else {
    const int n1 = (DI * DD) / 4;    // w1 granules (N=2048,K=512)
    const int n2 = n1;               // w2 granules (N=512, K=2048)
    int i = (blk - NLOGW_BLK) * 256 + threadIdx.x;
    float4 v;
    unsigned short* dst;
    size_t base;
    if (i < n1) {
      v = ((const float4*)w1)[i];
      dst = w1b;
      base = pk(i >> 7, (i & 127) * 4, DD);
    } else if (i < n1 + n2) {
      int j = i - n1;
      v = ((const float4*)w2)[j];
      dst = w2b;
      base = pk(j >> 9, (j & 511) * 4, DI);
    } else {
      int j = i - n1 - n2;
      v = ((const float4*)v_w)[j];
      dst = v_wb;
      base = pk(j >> 7, (j & 127) * 4, DD);
    }
    dst[base + 0] = f2b(v.x);
    dst[base + 1] = f2b(v.y);
    dst[base + 2] = f2b(v.z);
    dst[base + 3] = f2b(v.w);
  }
}

// ---------------------------------------------------------------------------
// K2: softmax + xa contraction -> xab (fragment-packed bf16).  (r10, proven)
// ---------------------------------------------------------------------------
__global__ __launch_bounds__(512) void xa_kernel(
    const float* __restrict__ x, const float* __restrict__ logits,
    float* __restrict__ attn_out, unsigned short* __restrict__ xab) {
  int bs = blockIdx.x >> 1, half = blockIdx.x & 1;
  int t = threadIdx.x, wv = t >> 6, lane = t & 63;

  __shared__ float sattn_t[LL][HH];
  __shared__ float sxa[2][HH][256];

  if (wv < 4) {
    for (int h = wv; h < HH; h += 4) {
      const float* lg = logits + ((size_t)bs * HH + h) * LL;
      float v0 = lg[lane], v1 = lg[lane + 64];
      float m = fmaxf(v0, v1);
#pragma unroll
      for (int off = 32; off > 0; off >>= 1) m = fmaxf(m, __shfl_xor(m, off));
      float e0 = __expf(v0 - m), e1 = __expf(v1 - m);
      float s = e0 + e1;
#pragma unroll
      for (int off = 32; off > 0; off >>= 1) s += __shfl_xor(s, off);
      float inv = 1.f / s;
      e0 *= inv; e1 *= inv;
      sattn_t[lane][h]      = e0;
      sattn_t[lane + 64][h] = e1;
      if (half == 0) {
        float* ao = attn_out + ((size_t)bs * HH + h) * LL;
        ao[lane]      = e0;
        ao[lane + 64] = e1;
      }
    }
  }
  __syncthreads();

  int col = t & 255, lseg = t >> 8;
  int e = half * 256 + col;
  const float* xb = x + (size_t)bs * LL * DD;
  float acc[HH];
#pragma unroll
  for (int h = 0; h < HH; ++h) acc[h] = 0.f;
  int l0 = lseg * 64;
  for (int l = l0; l < l0 + 64; ++l) {
    float xv = xb[(size_t)l * DD + e];
    float4 a0 = *(const float4*)&sattn_t[l][0];
    float4 a1 = *(const float4*)&sattn_t[l][4];
    acc[0] += a0.x * xv; acc[1] += a0.y * xv;
    acc[2] += a0.z * xv; acc[3] += a0.w * xv;
    acc[4] += a1.x * xv; acc[5] += a1.y * xv;
    acc[6] += a1.z * xv; acc[7] += a1.w * xv;
  }
#pragma unroll
  for (int h = 0; h < HH; ++h) sxa[lseg][h][col] = acc[h];
  __syncthreads();
  if (t < 256) {
#pragma unroll
    for (int h = 0; h < HH; ++h) {
      int m = bs * HH + h;
      xab[pk(m, e, DD)] = f2b(sxa[0][h][t] + sxa[1][h][t]);
    }
  }
}

// ---------------------------------------------------------------------------
// K3: GEMM_V  vpart[ks] = xa @ v_w^T.  M=1024 N=512 K=512, K-split x4. (r10)
// ---------------------------------------------------------------------------
__global__ __launch_bounds__(256) void gemm_v_kernel(
    const unsigned short* __restrict__ xab, const unsigned short* __restrict__ v_wb,
    float* __restrict__ vpart) {
  int blk = blockIdx.x;
  int nt = blk & 7, mt = (blk >> 3) & 15, kslice = blk >> 7;
  int wv = threadIdx.x >> 6, lane = threadIdx.x & 63;
  int lm = lane & 15, lq = lane >> 4;

  int m0 = mt * 64 + wv * 16;
  int n0 = nt * 64;
  const short8* A8 = (const short8*)xab + (size_t)(m0 >> 4) * 16 * 64;
  const short8* B8 = (const short8*)v_wb;

  float4v acc[4];
#pragma unroll
  for (int nf = 0; nf < 4; ++nf) acc[nf] = (float4v){0.f, 0.f, 0.f, 0.f};

#pragma unroll
  for (int ci = 0; ci < 4; ++ci) {
    int c = kslice * 4 + ci;
    short8 a = A8[(size_t)c * 64 + lane];
#pragma unroll
    for (int nf = 0; nf < 4; ++nf) {
      short8 b = B8[((size_t)((n0 >> 4) + nf) * 16 + c) * 64 + lane];
      acc[nf] = __builtin_amdgcn_mfma_f32_16x16x32_bf16(a, b, acc[nf], 0, 0, 0);
    }
  }

  float* outp = vpart + (size_t)kslice * SLICE;
#pragma unroll
  for (int nf = 0; nf < 4; ++nf) {
    int col = n0 + nf * 16 + lm;
#pragma unroll
    for (int r = 0; r < 4; ++r)
      outp[(size_t)(m0 + lq * 4 + r) * DD + col] = acc[nf][r];
  }
}

// ---------------------------------------------------------------------------
// K4: mid LayerNorm over 4 partials -> o_ln fp32 + o_lnb (packed bf16). (r10)
// ---------------------------------------------------------------------------
__global__ __launch_bounds__(256) void ln_mid_kernel(
    const float* __restrict__ vpart, const float* __restrict__ ln_g,
    const float* __restrict__ ln_b, float* __restrict__ o_ln,
    unsigned short* __restrict__ o_lnb) {
  int wv = threadIdx.x >> 6, lane = threadIdx.x & 63;
  int row = blockIdx.x * 4 + wv;

  const float* p0 = vpart + (size_t)row * DD;
  float vals[8];
  float sum = 0.f, sq = 0.f;
#pragma unroll
  for (int k = 0; k < 8; ++k) {
    int d = lane + 64 * k;
    float v = p0[d] + p0[SLICE + d] + p0[2 * SLICE + d] + p0[3 * SLICE + d];
    vals[k] = v;
    sum += v;
    sq += v * v;
  }
#pragma unroll
  for (int off = 32; off > 0; off >>= 1) {
    sum += __shfl_xor(sum, off);
    sq  += __shfl_xor(sq, off);
  }
  float mu  = sum * (1.f / DD);
  float var = sq * (1.f / DD) - mu * mu;
  float rs  = rsqrtf(var + EPSN);
  float* op = o_ln + (size_t)row * DD;
#pragma unroll
  for (int k = 0; k < 8; ++k) {
    int d = lane + 64 * k;
    float v = (vals[k] - mu) * rs * ln_g[d] + ln_b[d];
    op[d] = v;
    o_lnb[pk(row, d, DD)] = f2b(v);
  }
}

// ---------------------------------------------------------------------------
// K5: GEMM1  h1 = relu(xln @ w1^T + b1) -> h1b (packed, A-role K=2048). (r10)
// ---------------------------------------------------------------------------
__global__ __launch_bounds__(256) void gemm1_kernel(
    const unsigned short* __restrict__ o_lnb, const unsigned short* __restrict__ w1b,
    const float* __restrict__ b1, unsigned short* __restrict__ h1b) {
  int blk = blockIdx.x;
  int nt = blk & 31, mt = blk >> 5;
  int wv = threadIdx.x >> 6, lane = threadIdx.x & 63;
  int lm = lane & 15, lq = lane >> 4;

  int m0 = mt * 64 + wv * 16;
  int n0 = nt * 64;
  const short8* A8 = (const short8*)o_lnb + (size_t)(m0 >> 4) * 16 * 64;
  const short8* B8 = (const short8*)w1b;

  float4v acc[4];
#pragma unroll
  for (int nf = 0; nf < 4; ++nf) acc[nf] = (float4v){0.f, 0.f, 0.f, 0.f};

#pragma unroll 4
  for (int c = 0; c < 16; ++c) {
    short8 a = A8[(size_t)c * 64 + lane];
#pragma unroll
    for (int nf = 0; nf < 4; ++nf) {
      short8 b = B8[((size_t)((n0 >> 4) + nf) * 16 + c) * 64 + lane];
      acc[nf] = __builtin_amdgcn_mfma_f32_16x16x32_bf16(a, b, acc[nf], 0, 0, 0);
    }
  }

#pragma unroll
  for (int nf = 0; nf < 4; ++nf) {
    int col = n0 + nf * 16 + lm;
    float bb = b1[col];
#pragma unroll
    for (int r = 0; r < 4; ++r) {
      int row = m0 + lq * 4 + r;
      h1b[pk(row, col, DI)] = f2b(fmaxf(acc[nf][r] + bb, 0.f));
    }
  }
}

// ---------------------------------------------------------------------------
// K6: GEMM2  ypart[ks] = h1 @ w2^T.  M=1024 N=512 K=2048, K-split x4. (r10)
// ---------------------------------------------------------------------------
__global__ __launch_bounds__(256) void gemm2_kernel(
    const unsigned short* __restrict__ h1b, const unsigned short* __restrict__ w2b,
    float* __restrict__ ypart) {
  int blk = blockIdx.x;
  int nt = blk & 7, mt = (blk >> 3) & 15, kslice = blk >> 7;
  int wv = threadIdx.x >> 6, lane = threadIdx.x & 63;
  int lm = lane & 15, lq = lane >> 4;

  int m0 = mt * 64 + wv * 16;
  int n0 = nt * 64;
  const short8* A8 = (const short8*)h1b + (size_t)(m0 >> 4) * 64 * 64;   // K/32=64
  const short8* B8 = (const short8*)w2b;

  float4v acc[4];
#pragma unroll
  for (int nf = 0; nf < 4; ++nf) acc[nf] = (float4v){0.f, 0.f, 0.f, 0.f};

#pragma unroll 4
  for (int ci = 0; ci < 16; ++ci) {
    int c = kslice * 16 + ci;
    short8 a = A8[(size_t)c * 64 + lane];
#pragma unroll
    for (int nf = 0; nf < 4; ++nf) {
      short8 b = B8[((size_t)((n0 >> 4) + nf) * 64 + c) * 64 + lane];
      acc[nf] = __builtin_amdgcn_mfma_f32_16x16x32_bf16(a, b, acc[nf], 0, 0, 0);
    }
  }

  float* outp = ypart + (size_t)kslice * SLICE;
#pragma unroll
  for (int nf = 0; nf < 4; ++nf) {
    int col = n0 + nf * 16 + lm;
#pragma unroll
    for (int r = 0; r < 4; ++r)
      outp[(size_t)(m0 + lq * 4 + r) * DD + col] = acc[nf][r];
  }
}

// ---------------------------------------------------------------------------
// K7: final LN:  y = LN(sum ypart + b2 + o_ln)*g + b.  (r10)
// ---------------------------------------------------------------------------
__global__ __launch_bounds__(256) void ln_final_kernel(
    const float* __restrict__ ypart, const float* __restrict__ o_ln,
    const float* __restrict__ b2, const float* __restrict__ fln_g,
    const float* __restrict__ fln_b, float* __restrict__ y_out) {
  int wv = threadIdx.x >> 6, lane = threadIdx.x & 63;
  int row = blockIdx.x * 4 + wv;

  const float* p0 = ypart + (size_t)row * DD;
  const float* ol = o_ln + (size_t)row * DD;
  float vals[8];
  float sum = 0.f, sq = 0.f;
#pragma unroll
  for (int k = 0; k < 8; ++k) {
    int d = lane + 64 * k;
    float v = p0[d] + p0[SLICE + d] + p0[2 * SLICE + d] + p0[3 * SLICE + d] +
              b2[d] + ol[d];
    vals[k] = v;
    sum += v;
    sq += v * v;
  }
#pragma unroll
  for (int off = 32; off > 0; off >>= 1) {
    sum += __shfl_xor(sum, off);
    sq  += __shfl_xor(sq, off);
  }
  float mu  = sum * (1.f / DD);
  float var = sq * (1.f / DD) - mu * mu;
  float rs  = rsqrtf(var + EPSN);
  float* yo = y_out + (size_t)row * DD;
#pragma unroll
  for (int k = 0; k < 8; ++k) {
    int d = lane + 64 * k;
    yo[d] = (vals[k] - mu) * rs * fln_g[d] + fln_b[d];
  }
}

extern "C" void kernel_launch(void* const* d_in, const int* in_sizes, int n_in,
                              void* d_out, int out_size, void* d_ws, size_t ws_size,
                              hipStream_t stream) {
  const float* x     = (const float*)d_in[0];
  const int*   mask  = (const int*)d_in[1];
  const float* w     = (const float*)d_in[2];
  const float* v_w   = (const float*)d_in[3];
  const float* ln_g  = (const float*)d_in[4];
  const float* ln_b  = (const float*)d_in[5];
  const float* w1    = (const float*)d_in[6];
  const float* b1    = (const float*)d_in[7];
  const float* w2    = (const float*)d_in[8];
  const float* b2    = (const float*)d_in[9];
  const float* fln_g = (const float*)d_in[10];
  const float* fln_b = (const float*)d_in[11];

  float* y    = (float*)d_out;
  float* attn = y + (size_t)BB * SS * HH * DD;

  // workspace layout (bytes)
  char* ws = (char*)d_ws;
  float*          o_ln   = (float*)(ws);                       // 2 MB
  unsigned short* o_lnb  = (unsigned short*)(ws + 2097152);    // 1 MB
  unsigned short* w1b    = (unsigned short*)(ws + 3145728);    // 2 MB
  unsigned short* w2b    = (unsigned short*)(ws + 5242880);    // 2 MB
  unsigned short* h1b    = (unsigned short*)(ws + 7340032);    // 4 MB
  float*          ypart  = (float*)(ws + 11534336);            // 8 MB (4 slices)
  unsigned short* v_wb   = (unsigned short*)(ws + 19922944);   // 512 KB
  unsigned short* xab    = (unsigned short*)(ws + 20447232);   // 1 MB
  float*          vpart  = (float*)(ws + 21495808);            // 8 MB (4 slices)
  float*          logits = (float*)(ws + 29884416);            // 512 KB

  pre_kernel<<<NLOGW_BLK + NCAST_BLK, 256, 0, stream>>>(
      x, mask, w, w1, w2, v_w, w1b, w2b, v_wb, logits);
  xa_kernel<<<BB * SS * 2, 512, 0, stream>>>(x, logits, attn, xab);
  gemm_v_kernel<<<512, 256, 0, stream>>>(xab, v_wb, vpart);
  ln_mid_kernel<<<256, 256, 0, stream>>>(vpart, ln_g, ln_b, o_ln, o_lnb);
  gemm1_kernel<<<512, 256, 0, stream>>>(o_lnb, w1b, b1, h1b);
  gemm2_kernel<<<512, 256, 0, stream>>>(h1b, w2b, ypart);
  ln_final_kernel<<<256, 256, 0, stream>>>(ypart, o_ln, b2, fln_g, fln_b, y);
}